// Round 5
// baseline (915.515 us; speedup 1.0000x reference)
//
#include <hip/hip_runtime.h>
#include <hip/hip_bf16.h>

typedef unsigned short u16;
typedef unsigned int u32;
typedef __attribute__((ext_vector_type(8))) short bfrag8;
typedef __attribute__((ext_vector_type(4))) float f32x4;

#define ME_N 327660
#define MN_N 40962
#define MEMB_N 256
#define H1_N 512
#define H2_N 64
#define EEMB_N 256
#define LN_EPS 1e-5f
#define NBLK 5120  // ceil(ME/64)

static __device__ __forceinline__ u16 f2bf(float f) {
  __hip_bfloat16 h = __float2bfloat16(f);
  return *reinterpret_cast<u16*>(&h);
}
static __device__ __forceinline__ float bf2f(u16 u) {
  union { u32 i; float f; } x; x.i = ((u32)u) << 16; return x.f;
}
static __device__ __forceinline__ u32 pack2(float a, float b) {
  return (u32)f2bf(a) | ((u32)f2bf(b) << 16);
}
static __device__ __forceinline__ float silu_f(float x) {
  return x / (1.0f + __expf(-x));
}
static __device__ __forceinline__ void gload_lds16(const void* g, void* l) {
  __builtin_amdgcn_global_load_lds(
      (const __attribute__((address_space(1))) void*)g,
      (__attribute__((address_space(3))) void*)l, 16, 0, 0);
}

// ---- int32 -> float32 value conversion (harness reads whole out buf as f32) ----
__global__ void i2f_kernel(const int* __restrict__ src, float* __restrict__ dst, int n) {
  int i = blockIdx.x * 256 + threadIdx.x;
  if (i < n) dst[i] = (float)src[i];
}

// ---- mx fp32 -> bf16, straight copy, 8 elems/thread ----
__global__ void bfconv_kernel(const float* __restrict__ src, u16* __restrict__ dst, int n) {
  int i = (blockIdx.x * 256 + threadIdx.x) * 8;
  if (i >= n) return;
  float4 v0 = reinterpret_cast<const float4*>(src + i)[0];
  float4 v1 = reinterpret_cast<const float4*>(src + i)[1];
  uint4 q;
  q.x = pack2(v0.x, v0.y); q.y = pack2(v0.z, v0.w);
  q.z = pack2(v1.x, v1.y); q.w = pack2(v1.z, v1.w);
  *reinterpret_cast<uint4*>(dst + i) = q;
}

// ---- W1 -> fragment-contiguous bf16 layout [J=32][kc=12][ks=2][k4=4][l16=16][8]
//      element i holds W1[k][n], n=J*16+l16, k=kc*64+ks*32+k4*8+e
__global__ void wconv1_kernel(const float* __restrict__ src, u16* __restrict__ dst) {
  int i = blockIdx.x * 256 + threadIdx.x;
  if (i >= 512 * 768) return;
  int e   = i & 7;
  int l16 = (i >> 3) & 15;
  int k4  = (i >> 7) & 3;
  int ks  = (i >> 9) & 1;
  int rest = i >> 10;
  int kc = rest % 12;
  int J  = rest / 12;
  int n = J * 16 + l16;
  int k = kc * 64 + ks * 32 + k4 * 8 + e;
  dst[i] = f2bf(src[(size_t)k * 512 + n]);
}

// ---- generic weight transpose + bf16: dst[n*K+k] = src[k*N+n] ----
__global__ void wconv_kernel(const float* __restrict__ src, u16* __restrict__ dst,
                             int K, int N) {
  int i = blockIdx.x * 256 + threadIdx.x;
  if (i >= K * N) return;
  int n = i / K;
  int k = i - n * K;
  dst[i] = f2bf(src[(size_t)k * N + n]);
}

// ---- fused MLP, 512 threads / 8 waves / 64 rows per block, swapped-operand MFMA.
//      acc holds transposed outputs -> packed b64 LDS stores everywhere.
__launch_bounds__(512, 4)
__global__ void gemm_fused_kernel(const u16* __restrict__ mxb, const int* __restrict__ me_i,
                                  const float* __restrict__ me_x,
                                  const u16* __restrict__ w1f, const float* __restrict__ b1,
                                  const u16* __restrict__ w2t, const float* __restrict__ b2,
                                  const u16* __restrict__ w3t, const float* __restrict__ b3,
                                  u16* __restrict__ h3, float* __restrict__ partials) {
  // S reuse timeline (u16 idx):
  //  main loop : Abuf dbuf [0,8192)
  //  phase1/2  : h1T half [0,16384) stride 256, group-XOR swizzle
  //  reduce    : LDSf f32[4096] = [0,8192) ; h2T [12288,16384) stride 64, swizzled
  //  phase3    : h3s [0,16384) stride 256, swizzled
  __shared__ u16 S[16384];
  __shared__ float red[16];

  const int t = threadIdx.x;
  const int m0 = blockIdx.x * 64;
  const int lane = t & 63;
  const int w = t >> 6;
  const int l16 = lane & 15;
  const int k4 = lane >> 4;
  const int h7 = l16 & 7;

  // --- staging mapping: thread -> (row r_st, 8-elem group g_st), source pre-swizzled
  const int r_st = t >> 3;
  const int g_st = t & 7;
  const int gsw = ((g_st ^ (r_st & 7)) * 8);
  const int mg = min(m0 + r_st, ME_N - 1);
  const u16* rowr = mxb + (size_t)me_i[mg] * MEMB_N;
  const u16* rowc = mxb + (size_t)me_i[ME_N + mg] * MEMB_N;
  const float* pe = me_x + (size_t)mg * EEMB_N;

  const f32x4 zero = {0.f, 0.f, 0.f, 0.f};
  f32x4 acc[4][4];  // [jj: n1-frag][i: m-frag], value h1^T[n1][m]
#pragma unroll
  for (int jj = 0; jj < 4; ++jj)
#pragma unroll
    for (int i = 0; i < 4; ++i) acc[jj][i] = zero;

  auto stage_A = [&](int kcn) {
    const int buf = (kcn & 1) * 4096;
    if (kcn < 8) {
      const u16* src = (kcn < 4 ? rowr : rowc) + (kcn & 3) * 64 + gsw;
      gload_lds16(src, S + buf + w * 512);
    } else {
      const float4* p4 = reinterpret_cast<const float4*>(pe + (kcn - 8) * 64 + g_st * 8);
      float4 v0 = p4[0], v1 = p4[1];
      uint4 q;
      q.x = pack2(v0.x, v0.y); q.y = pack2(v0.z, v0.w);
      q.z = pack2(v1.x, v1.y); q.w = pack2(v1.z, v1.w);
      *reinterpret_cast<uint4*>(S + buf + r_st * 64 + gsw) = q;
    }
  };

  stage_A(0);
  __syncthreads();

  // ================= main loop: acc = (W1^T)(edge^T), i.e. h1^T =================
  for (int kc = 0; kc < 12; ++kc) {
    if (kc < 11) stage_A(kc + 1);
    const u16* ab = S + (kc & 1) * 4096;
    const u16* wb = w1f + (size_t)w * 12288 + (size_t)kc * 1024 + k4 * 128 + l16 * 8;
#pragma unroll
    for (int ks = 0; ks < 2; ++ks) {
      bfrag8 a[4];
#pragma unroll
      for (int i = 0; i < 4; ++i)
        a[i] = *reinterpret_cast<const bfrag8*>(
            &ab[(i * 16 + l16) * 64 + (((ks * 4 + k4) ^ h7) * 8)]);
#pragma unroll
      for (int jj = 0; jj < 4; ++jj) {
        bfrag8 bf = *reinterpret_cast<const bfrag8*>(wb + (size_t)jj * 98304 + ks * 512);
#pragma unroll
        for (int i = 0; i < 4; ++i)
          acc[jj][i] = __builtin_amdgcn_mfma_f32_16x16x32_bf16(bf, a[i], acc[jj][i], 0, 0, 0);
      }
    }
    __syncthreads();
  }

  // ====== phases 1+2 interleaved over two k-halves of layer 2 ======
  const int kh = w >> 2;    // which k-half this wave computes in phase 2
  const int g4 = w & 3;     // n2-slice / reduce group
  const int n2 = g4 * 16 + l16;
  bfrag8 w2f8[8];
#pragma unroll
  for (int ksl = 0; ksl < 8; ++ksl)
    w2f8[ksl] = *reinterpret_cast<const bfrag8*>(
        w2t + (size_t)n2 * 512 + kh * 256 + ksl * 32 + k4 * 8);

  f32x4 acc2p[4];
#pragma unroll
  for (int i = 0; i < 4; ++i) acc2p[i] = zero;

#pragma unroll
  for (int h = 0; h < 2; ++h) {
    // all waves write their jj = 2h, 2h+1 slices (n1-local, swizzled groups)
#pragma unroll
    for (int jr = 0; jr < 2; ++jr) {
      const int jj = 2 * h + jr;
      const float4 bq = *reinterpret_cast<const float4*>(b1 + jj * 128 + w * 16 + k4 * 4);
      const int col = jr * 128 + w * 16 + k4 * 4;
      const int grp = col >> 3, off = col & 7;
#pragma unroll
      for (int i = 0; i < 4; ++i) {
        float x0 = silu_f(acc[jj][i][0] + bq.x);
        float x1 = silu_f(acc[jj][i][1] + bq.y);
        float x2 = silu_f(acc[jj][i][2] + bq.z);
        float x3 = silu_f(acc[jj][i][3] + bq.w);
        uint2 pq = make_uint2(pack2(x0, x1), pack2(x2, x3));
        *reinterpret_cast<uint2*>(&S[(i * 16 + l16) * 256 + ((grp ^ h7) * 8 + off)]) = pq;
      }
    }
    __syncthreads();
    if (kh == h) {
#pragma unroll
      for (int ksl = 0; ksl < 8; ++ksl) {
#pragma unroll
        for (int i = 0; i < 4; ++i) {
          bfrag8 a2 = *reinterpret_cast<const bfrag8*>(
              &S[(i * 16 + l16) * 256 + (((ksl * 4 + k4) ^ h7) * 8)]);
          acc2p[i] = __builtin_amdgcn_mfma_f32_16x16x32_bf16(w2f8[ksl], a2, acc2p[i], 0, 0, 0);
        }
      }
    }
    __syncthreads();
  }

  // ====== cross-half reduce of layer 2, silu, h2T ======
  float* LDSf = reinterpret_cast<float*>(S);
  u16* h2T = S + 12288;
  if (kh == 1) {
#pragma unroll
    for (int i = 0; i < 4; ++i)
      *reinterpret_cast<f32x4*>(&LDSf[((g4 * 4 + i) * 64 + lane) * 4]) = acc2p[i];
  }
  __syncthreads();
  if (kh == 0) {
    const float4 b2q = *reinterpret_cast<const float4*>(b2 + g4 * 16 + k4 * 4);
    const int col = g4 * 16 + k4 * 4;
    const int grp = col >> 3, off = col & 7;
#pragma unroll
    for (int i = 0; i < 4; ++i) {
      f32x4 o = *reinterpret_cast<f32x4*>(&LDSf[((g4 * 4 + i) * 64 + lane) * 4]);
      float x0 = silu_f(acc2p[i][0] + o[0] + b2q.x);
      float x1 = silu_f(acc2p[i][1] + o[1] + b2q.y);
      float x2 = silu_f(acc2p[i][2] + o[2] + b2q.z);
      float x3 = silu_f(acc2p[i][3] + o[3] + b2q.w);
      uint2 pq = make_uint2(pack2(x0, x1), pack2(x2, x3));
      *reinterpret_cast<uint2*>(&h2T[(i * 16 + l16) * 64 + ((grp ^ h7) * 8 + off)]) = pq;
    }
  }
  __syncthreads();

  // ====== phase 3: h3^T = (W3^T)(h2^T) ; LN sums ; staged coalesced write ======
  bfrag8 a3[2][4];
#pragma unroll
  for (int ks = 0; ks < 2; ++ks)
#pragma unroll
    for (int i = 0; i < 4; ++i)
      a3[ks][i] = *reinterpret_cast<const bfrag8*>(
          &h2T[(i * 16 + l16) * 64 + (((ks * 4 + k4) ^ h7) * 8)]);
  bfrag8 w3f[2][2];
#pragma unroll
  for (int j = 0; j < 2; ++j)
#pragma unroll
    for (int ks = 0; ks < 2; ++ks)
      w3f[j][ks] = *reinterpret_cast<const bfrag8*>(
          w3t + (size_t)(w * 32 + j * 16 + l16) * 64 + ks * 32 + k4 * 8);
  __syncthreads();  // h2T reads done; S reusable as h3s

  f32x4 acc3[2][4];
#pragma unroll
  for (int j = 0; j < 2; ++j)
#pragma unroll
    for (int i = 0; i < 4; ++i) acc3[j][i] = zero;
#pragma unroll
  for (int ks = 0; ks < 2; ++ks)
#pragma unroll
    for (int j = 0; j < 2; ++j)
#pragma unroll
      for (int i = 0; i < 4; ++i)
        acc3[j][i] = __builtin_amdgcn_mfma_f32_16x16x32_bf16(w3f[j][ks], a3[ks][i], acc3[j][i], 0, 0, 0);

  float lsum = 0.f, lsq = 0.f;
#pragma unroll
  for (int j = 0; j < 2; ++j) {
    const float4 b3q = *reinterpret_cast<const float4*>(b3 + w * 32 + j * 16 + k4 * 4);
    const int col = w * 32 + j * 16 + k4 * 4;
    const int grp = col >> 3, off = col & 7;
#pragma unroll
    for (int i = 0; i < 4; ++i) {
      float x0 = acc3[j][i][0] + b3q.x;
      float x1 = acc3[j][i][1] + b3q.y;
      float x2 = acc3[j][i][2] + b3q.z;
      float x3 = acc3[j][i][3] + b3q.w;
      if (m0 + i * 16 + l16 < ME_N) {
        lsum += (x0 + x1) + (x2 + x3);
        lsq += x0 * x0 + x1 * x1 + x2 * x2 + x3 * x3;
      }
      uint2 pq = make_uint2(pack2(x0, x1), pack2(x2, x3));
      *reinterpret_cast<uint2*>(&S[(i * 16 + l16) * 256 + ((grp ^ h7) * 8 + off)]) = pq;
    }
  }
#pragma unroll
  for (int o = 32; o > 0; o >>= 1) {
    lsum += __shfl_down(lsum, o, 64);
    lsq  += __shfl_down(lsq, o, 64);
  }
  if (lane == 0) { red[w] = lsum; red[8 + w] = lsq; }
  __syncthreads();

  // coalesced global write of the [64][256] tile (h3 padded -> no row mask)
  {
    u16* dst = h3 + (size_t)(m0 + r_st) * EEMB_N;
#pragma unroll
    for (int q = 0; q < 4; ++q) {
      const int G = q * 8 + g_st;
      uint4 v = *reinterpret_cast<const uint4*>(&S[r_st * 256 + ((G ^ (r_st & 7)) * 8)]);
      *reinterpret_cast<uint4*>(dst + G * 8) = v;
    }
  }
  if (t == 0) {
    float s1 = 0.f, s2 = 0.f;
#pragma unroll
    for (int q = 0; q < 8; ++q) { s1 += red[q]; s2 += red[8 + q]; }
    partials[2 * blockIdx.x] = s1;
    partials[2 * blockIdx.x + 1] = s2;
  }
}

// ---- deterministic two-stage stats reduce ----
__global__ void reduce_kernel(const float* __restrict__ partials, int n,
                              float* __restrict__ stats) {
  __shared__ float s1[256], s2[256];
  float a = 0.f, b = 0.f;
  for (int i = threadIdx.x; i < n; i += 256) { a += partials[2 * i]; b += partials[2 * i + 1]; }
  s1[threadIdx.x] = a; s2[threadIdx.x] = b;
  __syncthreads();
  for (int off = 128; off > 0; off >>= 1) {
    if ((int)threadIdx.x < off) {
      s1[threadIdx.x] += s1[threadIdx.x + off];
      s2[threadIdx.x] += s2[threadIdx.x + off];
    }
    __syncthreads();
  }
  if (threadIdx.x == 0) {
    double cnt = (double)ME_N * (double)EEMB_N;
    double mean = (double)s1[0] / cnt;
    double var = (double)s2[0] / cnt - mean * mean;
    stats[0] = (float)mean;
    stats[1] = (float)(1.0 / sqrt(var + (double)LN_EPS));
  }
}

// ---- final: me_x + (h3-mean)*rstd*ln_w + ln_b ----
__launch_bounds__(256)
__global__ void final_kernel(const u16* __restrict__ h3, const float* __restrict__ me_x,
                             const float* __restrict__ ln_w, const float* __restrict__ ln_b,
                             const float* __restrict__ stats, float* __restrict__ out) {
  const size_t total = (size_t)ME_N * EEMB_N;
  size_t i = ((size_t)blockIdx.x * 256 + threadIdx.x) * 8;
  if (i >= total) return;
  const float mean = stats[0], inv = stats[1];
  uint4 hv = *reinterpret_cast<const uint4*>(h3 + i);
  float h[8];
  h[0] = bf2f((u16)(hv.x & 0xffff)); h[1] = bf2f((u16)(hv.x >> 16));
  h[2] = bf2f((u16)(hv.y & 0xffff)); h[3] = bf2f((u16)(hv.y >> 16));
  h[4] = bf2f((u16)(hv.z & 0xffff)); h[5] = bf2f((u16)(hv.z >> 16));
  h[6] = bf2f((u16)(hv.w & 0xffff)); h[7] = bf2f((u16)(hv.w >> 16));
  float4 m0 = reinterpret_cast<const float4*>(me_x + i)[0];
  float4 m1 = reinterpret_cast<const float4*>(me_x + i)[1];
  float4 w0 = reinterpret_cast<const float4*>(ln_w + i)[0];
  float4 w1 = reinterpret_cast<const float4*>(ln_w + i)[1];
  float4 c0 = reinterpret_cast<const float4*>(ln_b + i)[0];
  float4 c1 = reinterpret_cast<const float4*>(ln_b + i)[1];
  float4 o0, o1;
  o0.x = m0.x + (h[0] - mean) * inv * w0.x + c0.x;
  o0.y = m0.y + (h[1] - mean) * inv * w0.y + c0.y;
  o0.z = m0.z + (h[2] - mean) * inv * w0.z + c0.z;
  o0.w = m0.w + (h[3] - mean) * inv * w0.w + c0.w;
  o1.x = m1.x + (h[4] - mean) * inv * w1.x + c1.x;
  o1.y = m1.y + (h[5] - mean) * inv * w1.y + c1.y;
  o1.z = m1.z + (h[6] - mean) * inv * w1.z + c1.z;
  o1.w = m1.w + (h[7] - mean) * inv * w1.w + c1.w;
  reinterpret_cast<float4*>(out + i)[0] = o0;
  reinterpret_cast<float4*>(out + i)[1] = o1;
}

extern "C" void kernel_launch(void* const* d_in, const int* in_sizes, int n_in,
                              void* d_out, int out_size, void* d_ws, size_t ws_size,
                              hipStream_t stream) {
  const float* mx   = (const float*)d_in[1];
  const int*   me_i = (const int*)d_in[2];
  const float* me_x = (const float*)d_in[3];
  const float* W1 = (const float*)d_in[8];
  const float* b1 = (const float*)d_in[9];
  const float* W2 = (const float*)d_in[10];
  const float* b2 = (const float*)d_in[11];
  const float* W3 = (const float*)d_in[12];
  const float* b3 = (const float*)d_in[13];
  const float* ln_w = (const float*)d_in[14];
  const float* ln_b = (const float*)d_in[15];

  // workspace layout (bytes)
  char* ws = (char*)d_ws;
  u16* w1f = (u16*)(ws + 0);            // frag-layout W1 bf16 = 786432 B
  u16* w2t = (u16*)(ws + 786432);       // [64][512]  bf16 = 65536 B
  u16* w3t = (u16*)(ws + 851968);       // [256][64]  bf16 = 32768 B
  u16* mxb = (u16*)(ws + 884736);       // [MN][256]  bf16 = 20972544 B
  u16* h3  = (u16*)(ws + 21857280);     // [327680][256] bf16 padded = 167772160 B
  float* partials = (float*)(ws + 189629440);  // NBLK*2*4 = 40960 B
  float* stats    = (float*)(ws + 189670400);  // 2 floats

  // output offsets: tuple order == input order, slot 3 replaced by me_x_new
  size_t off[8]; size_t a = 0;
  for (int i = 0; i < 8; ++i) { off[i] = a; a += (size_t)in_sizes[i]; }

  // pass-through: float arrays raw-copied; int index arrays converted to f32 VALUES
  for (int i = 0; i < 8; ++i) {
    if (i == 3) continue;
    if (i == 2 || i == 4 || i == 6) {
      int n = in_sizes[i];
      i2f_kernel<<<(n + 255) / 256, 256, 0, stream>>>(
          (const int*)d_in[i], (float*)d_out + off[i], n);
    } else {
      hipMemcpyAsync((char*)d_out + off[i] * 4, d_in[i], (size_t)in_sizes[i] * 4,
                     hipMemcpyDeviceToDevice, stream);
    }
  }

  // weight / input conversions
  wconv1_kernel<<<(512 * 768 + 255) / 256, 256, 0, stream>>>(W1, w1f);
  wconv_kernel<<<(512 * 64 + 255) / 256, 256, 0, stream>>>(W2, w2t, 512, 64);
  wconv_kernel<<<(64 * 256 + 255) / 256, 256, 0, stream>>>(W3, w3t, 64, 256);
  {
    int n = MN_N * MEMB_N;  // divisible by 8
    bfconv_kernel<<<(n / 8 + 255) / 256, 256, 0, stream>>>(mx, mxb, n);
  }

  gemm_fused_kernel<<<NBLK, 512, 0, stream>>>(mxb, me_i, me_x, w1f, b1, w2t, b2,
                                              w3t, b3, h3, partials);
  reduce_kernel<<<1, 256, 0, stream>>>(partials, NBLK, stats);

  const size_t total8 = (size_t)ME_N * EEMB_N / 8;
  final_kernel<<<(int)((total8 + 255) / 256), 256, 0, stream>>>(
      h3, me_x, ln_w, ln_b, stats, (float*)d_out + off[3]);
}